// Round 13
// baseline (768.738 us; speedup 1.0000x reference)
//
#include <hip/hip_runtime.h>
#include <hip/hip_bf16.h>

#define SEQ 120
#define CELLS 30          // real cells (ci<5); row ci=5 is pad-only, precomputed
#define RDIM 48
#define BQ 4096
#define PBATCH 8
#define MAIN_BLOCKS (BQ/PBATCH)   // 512
#define ABUF 61440                // [120 tokens][512B] bf16 per buffer
#define YOFF 122880               // Y: [32][512B] after the two A buffers

typedef __bf16 bf16x8 __attribute__((ext_vector_type(8)));
typedef __bf16 bf16x4 __attribute__((ext_vector_type(4)));
typedef float  f32x4  __attribute__((ext_vector_type(4)));

__device__ __forceinline__ float gelu_f(float x){
  return 0.5f * x * (1.0f + erff(x * 0.7071067811865476f));
}
__device__ __forceinline__ bf16x8 pack8(f32x4 a, f32x4 b){
  bf16x8 r;
  r[0]=(__bf16)a[0]; r[1]=(__bf16)a[1]; r[2]=(__bf16)a[2]; r[3]=(__bf16)a[3];
  r[4]=(__bf16)b[0]; r[5]=(__bf16)b[1]; r[6]=(__bf16)b[2]; r[7]=(__bf16)b[3];
  return r;
}
__device__ __forceinline__ bf16x4 pack4(f32x4 a){
  bf16x4 r;
  r[0]=(__bf16)a[0]; r[1]=(__bf16)a[1]; r[2]=(__bf16)a[2]; r[3]=(__bf16)a[3];
  return r;
}

// ---------------- prep: weight repack (fp32->bf16) + pad-cell readout Gpad ----------------
__global__ void prep_kernel(const float* __restrict__ conv_w, const float* __restrict__ conv_b,
                            const float* __restrict__ P,
                            const float* __restrict__ red_w, const float* __restrict__ red_b,
                            const float* __restrict__ res_w1, const float* __restrict__ res_w2,
                            __bf16* __restrict__ W_bt, __bf16* __restrict__ W_red,
                            __bf16* __restrict__ W1p, __bf16* __restrict__ W2p,
                            float* __restrict__ Gpad)
{
  const int b = blockIdx.x, t = threadIdx.x;
  if (b < 256){
    // W_bt[o][k], k = pos*256 + c  (pos = kh*2+kw)
    #pragma unroll
    for (int u=0;u<4;u++){
      int k = u*256 + t;
      W_bt[b*1024 + k] = (__bf16)conv_w[b*1024 + (k&255)*4 + (k>>8)];
    }
  } else if (b == 256){
    for (int i=t; i<48*256; i+=256) W_red[i] = (__bf16)red_w[i];
  } else if (b < 273){
    int l = b - 257;
    #pragma unroll
    for (int u=0;u<12;u++){
      int idx = u*256 + t;               // j*64 + k
      int j = idx >> 6, k = idx & 63;
      W1p[l*3072 + idx] = (k < 48) ? (__bf16)res_w1[(l*48+j)*48 + k] : (__bf16)0.0f;
    }
  } else if (b < 289){
    int l = b - 273;
    #pragma unroll
    for (int u=0;u<12;u++){
      int idx = u*256 + t;
      int j = idx >> 6, k = idx & 63;
      W2p[l*3072 + idx] = (k < 48) ? (__bf16)res_w2[(l*48+j)*48 + k] : (__bf16)0.0f;
    }
  } else {
    // Gpad: full fp32 readout of the all-pad patch (all 4 positions = P)
    __shared__ float tg[256];
    float z = conv_b[t];
    for (int c=0;c<256;c++){
      const float* w = conv_w + t*1024 + c*4;
      z += (w[0]+w[1]+w[2]+w[3]) * P[c];
    }
    tg[t] = gelu_f(z);
    __syncthreads();
    if (t < 48){
      float g = red_b[t];
      for (int o=0;o<256;o++) g += red_w[t*256+o]*tg[o];
      Gpad[t] = gelu_f(g);
    }
  }
}

// ---------------- main: producer/consumer wave-specialized batch GEMM ----------------
// Block = 8 batches. 4 producer waves stream batch i+1's 120 tokens (120KB LINEAR HBM read,
// chunk-pipelined reg-stage -> bf16 LDS; their vmcnt FIFO holds ONLY stage loads).
// 4 consumer waves run the full K=1024 patch-GEMM for batch i (A from LDS via per-lane
// token indirection; B per-wave from L2-resident W_bt -- their FIFO holds ONLY B loads).
// Decouples the two vmem streams that serialized R4-R12. 2 barriers per phase.
__global__ __launch_bounds__(512, 1) void main_kernel(
    const float* __restrict__ X, const __bf16* __restrict__ W_bt,
    const float* __restrict__ conv_b, const __bf16* __restrict__ W_red,
    const float* __restrict__ red_b, float* __restrict__ G)
{
  __shared__ __align__(16) char sm[139264];   // A dbuf 2x61440 + Y 16384
  const int tid  = threadIdx.x;
  const int lane = tid & 63;
  const int wave = tid >> 6;                 // 0..3 consumer, 4..7 producer
  const int lr = lane & 15, lk = lane >> 4;
  const int b0 = blockIdx.x * PBATCH;

  // ---- consumer constants
  const int cw = wave;                        // consumer col-quadrant (only used if wave<4)
  const int c0  = lr;                         // Mtile0 cell (0..15)
  const int c1r = 16 + lr;                    // Mtile1 cell (16..31)
  const int c1  = (c1r < 30) ? c1r : 0;       // clamp garbage rows to a valid token
  const int tb0 = 24*(c0/6) + 2*(c0 - (c0/6)*6);
  const int tb1 = 24*(c1/6) + 2*(c1 - (c1/6)*6);
  const __bf16* bb[4];
  #pragma unroll
  for (int ni=0; ni<4; ++ni)
    bb[ni] = W_bt + (size_t)(((wave&3)*64) + ni*16 + lr)*1024 + lk*8;

  // ---- producer constants
  const int pw = wave - 4;                    // 0..3 (only used if wave>=4)
  const int tkbase = (wave >= 4) ? pw*30 : 0; // tokens [pw*30, pw*30+30)

  // producer: stage batch bi into buffer d (2-deep chunk pipeline, 5 chunks of 6 tokens)
  auto STAGE = [&](int bi, int d){
    char* dst = sm + d*ABUF;
    const char* src = (const char*)X + ((size_t)(b0+bi)*SEQ)*1024 + lane*16;
    f32x4 pa[6], pb[6];
    auto LOADC = [&](int c, f32x4* arr){
      #pragma unroll
      for (int j=0;j<6;j++) arr[j] = *(const f32x4*)(src + (size_t)(tkbase + c*6 + j)*1024);
    };
    auto WRITEC = [&](int c, const f32x4* arr){
      #pragma unroll
      for (int j=0;j<6;j++){
        int tk = tkbase + c*6 + j;
        *(bf16x4*)(dst + tk*512 + ((lane*8) ^ (((tk>>1)&7)<<4))) = pack4(arr[j]);
      }
    };
    LOADC(0, pa);
    LOADC(1, pb); WRITEC(0, pa);
    LOADC(2, pa); WRITEC(1, pb);
    LOADC(3, pb); WRITEC(2, pa);
    LOADC(4, pa); WRITEC(3, pb);
    WRITEC(4, pa);
  };

  // prologue: producers stage batch 0 into buf0
  if (wave >= 4) STAGE(0, 0);
  __syncthreads();

  for (int i=0; i<PBATCH; ++i){
    if (wave < 4){
      // -------- consumer: full GEMM for batch i from buf[i&1] --------
      const char* ab = sm + (i&1)*ABUF;
      f32x4 acc[2][4];
      #pragma unroll
      for (int a=0;a<2;a++)
        #pragma unroll
        for (int b=0;b<4;b++) acc[a][b] = (f32x4){0.f,0.f,0.f,0.f};
      #pragma unroll
      for (int s=0; s<16; ++s){              // k = s*64 + ks*32 (same order as prior rounds)
        const int p = s>>2, q = s&3;
        const int toff = (p>>1)*12 + (p&1);
        const int t0 = tb0 + toff, t1 = tb1 + toff;
        const int k0 = ((t0>>1)&7)<<4, k1 = ((t1>>1)&7)<<4;
        #pragma unroll
        for (int ks=0; ks<2; ++ks){
          bf16x8 bv[4];
          #pragma unroll
          for (int ni=0; ni<4; ++ni)
            bv[ni] = *(const bf16x8*)(bb[ni] + s*64 + ks*32);
          const int ib = q*128 + ks*64 + lk*16;
          bf16x8 a0 = *(const bf16x8*)(ab + t0*512 + (ib ^ k0));
          bf16x8 a1 = *(const bf16x8*)(ab + t1*512 + (ib ^ k1));
          #pragma unroll
          for (int ni=0; ni<4; ++ni){
            acc[0][ni] = __builtin_amdgcn_mfma_f32_16x16x32_bf16(a0, bv[ni], acc[0][ni], 0,0,0);
            acc[1][ni] = __builtin_amdgcn_mfma_f32_16x16x32_bf16(a1, bv[ni], acc[1][ni], 0,0,0);
          }
        }
      }
      // epilogue 1: conv bias + gelu -> Y bf16 [32][512B] (rows 30,31 garbage, guarded later)
      #pragma unroll
      for (int ni=0; ni<4; ++ni){
        const int col = cw*64 + ni*16 + lr;
        const float cb = conv_b[col];
        #pragma unroll
        for (int mi=0; mi<2; ++mi){
          #pragma unroll
          for (int reg=0; reg<4; ++reg){
            int row = mi*16 + lk*4 + reg;
            float y = gelu_f(acc[mi][ni][reg] + cb);
            *(__bf16*)(sm + YOFF + ((row*512 + col*2) ^ ((row&7)<<4))) = (__bf16)y;
          }
        }
      }
    } else {
      // -------- producer: stage batch i+1 into buf[(i+1)&1] --------
      if (i+1 < PBATCH) STAGE(i+1, (i+1)&1);
    }
    __syncthreads();

    if (wave < 2){
      // -------- GEMM2: G = gelu(Y @ red_w^T + red_b); waves 0,1 own 16 rows each --------
      f32x4 acc2[3];
      #pragma unroll
      for (int nf=0;nf<3;nf++) acc2[nf] = (f32x4){0.f,0.f,0.f,0.f};
      const int rowY = cw*16 + lr;
      const int keyY = (rowY&7)<<4;
      #pragma unroll
      for (int kk=0; kk<8; ++kk){
        bf16x8 a2 = *(const bf16x8*)(sm + YOFF + ((rowY*512 + kk*64 + lk*16) ^ keyY));
        #pragma unroll
        for (int nf=0; nf<3; ++nf){
          bf16x8 b2 = *(const bf16x8*)(W_red + (size_t)(nf*16+lr)*256 + kk*32 + lk*8);
          acc2[nf] = __builtin_amdgcn_mfma_f32_16x16x32_bf16(a2, b2, acc2[nf], 0,0,0);
        }
      }
      #pragma unroll
      for (int nf=0; nf<3; ++nf){
        float rb = red_b[nf*16+lr];
        #pragma unroll
        for (int reg=0; reg<4; ++reg){
          int lrow = cw*16 + lk*4 + reg;
          if (lrow < 30)
            G[((size_t)(b0+i)*CELLS + lrow)*RDIM + nf*16 + lr] = gelu_f(acc2[nf][reg] + rb);
        }
      }
    }
    __syncthreads();
  }
}

// ---------------- head: pool + 16 residual blocks (bf16 MFMA, K padded to 64) + linear ----------------
__global__ __launch_bounds__(64) void head_kernel(
    const float* __restrict__ G, const float* __restrict__ Gpad,
    const __bf16* __restrict__ W1p, const __bf16* __restrict__ W2p,
    const float* __restrict__ res_b1, const float* __restrict__ res_b2,
    const float* __restrict__ out_w, const float* __restrict__ out_b,
    float* __restrict__ out)
{
  __shared__ __align__(16) char Hs[16*256];  // [16 rows][64 f32], swizzled, cols 48..63 = 0
  __shared__ __align__(16) char Ys[16*256];
  const int t = threadIdx.x;                 // one wave
  const int lr = t & 15, lk = t >> 4;
  const int b0 = blockIdx.x * 16;

  { // zero pad cols 48..63 (stay zero: layers only write cols<48)
    int row = t >> 2, j4 = 12 + (t & 3);
    int off = (row*256 + j4*16) ^ ((row&7)<<5);
    *(f32x4*)(Hs + off) = (f32x4){0,0,0,0};
    *(f32x4*)(Ys + off) = (f32x4){0,0,0,0};
  }

  // pool: H[b][j] = (sum_{c<30} G[b][c][j] + 6*Gpad[j]) / 36
  #pragma unroll
  for (int pp=0; pp<3; ++pp){
    int idx = pp*64 + t;
    int b = idx / 12, j4 = idx - b*12;
    f32x4 s = ((const f32x4*)Gpad)[j4] * 6.0f;
    const float* g = G + ((size_t)(b0+b)*CELLS)*RDIM + j4*4;
    #pragma unroll
    for (int c=0;c<CELLS;c++) s += *(const f32x4*)(g + c*RDIM);
    s *= (1.0f/36.0f);
    *(f32x4*)(Hs + ((b*256 + j4*16) ^ ((b&7)<<5))) = s;
  }
  __syncthreads();

  const int rowA = lr;
  const int keyA = (rowA&7)<<5;
  for (int l=0; l<16; ++l){
    bf16x8 a[2];
    #pragma unroll
    for (int kk=0;kk<2;kk++){
      f32x4 u0 = *(const f32x4*)(Hs + ((rowA*256 + kk*128 + lk*32) ^ keyA));
      f32x4 u1 = *(const f32x4*)(Hs + ((rowA*256 + kk*128 + lk*32 + 16) ^ keyA));
      a[kk] = pack8(u0,u1);
    }
    #pragma unroll
    for (int nf=0; nf<3; ++nf){
      f32x4 acc = (f32x4){0,0,0,0};
      #pragma unroll
      for (int kk=0;kk<2;kk++){
        bf16x8 bw = *(const bf16x8*)(W1p + ((size_t)l*48 + nf*16 + lr)*64 + kk*32 + lk*8);
        acc = __builtin_amdgcn_mfma_f32_16x16x32_bf16(a[kk], bw, acc, 0,0,0);
      }
      float bj = res_b1[l*48 + nf*16 + lr];
      #pragma unroll
      for (int reg=0; reg<4; ++reg){
        int row = lk*4 + reg;
        *(float*)(Ys + ((row*256 + (nf*16+lr)*4) ^ ((row&7)<<5))) = gelu_f(acc[reg] + bj);
      }
    }
    __syncthreads();
    bf16x8 a2[2];
    #pragma unroll
    for (int kk=0;kk<2;kk++){
      f32x4 u0 = *(const f32x4*)(Ys + ((rowA*256 + kk*128 + lk*32) ^ keyA));
      f32x4 u1 = *(const f32x4*)(Ys + ((rowA*256 + kk*128 + lk*32 + 16) ^ keyA));
      a2[kk] = pack8(u0,u1);
    }
    #pragma unroll
    for (int nf=0; nf<3; ++nf){
      f32x4 acc = (f32x4){0,0,0,0};
      #pragma unroll
      for (int kk=0;kk<2;kk++){
        bf16x8 bw = *(const bf16x8*)(W2p + ((size_t)l*48 + nf*16 + lr)*64 + kk*32 + lk*8);
        acc = __builtin_amdgcn_mfma_f32_16x16x32_bf16(a2[kk], bw, acc, 0,0,0);
      }
      float bj = res_b2[l*48 + nf*16 + lr];
      #pragma unroll
      for (int reg=0; reg<4; ++reg){
        int row = lk*4 + reg;
        float* hp = (float*)(Hs + ((row*256 + (nf*16+lr)*4) ^ ((row&7)<<5)));
        *hp += acc[reg] + bj;
      }
    }
    __syncthreads();
  }

  float s = 0.f;
  #pragma unroll
  for (int i=0;i<12;i++){
    int j = lk*12 + i;
    s += *(const float*)(Hs + ((lr*256 + j*4) ^ ((lr&7)<<5))) * out_w[j];
  }
  s += __shfl_xor(s, 16);
  s += __shfl_xor(s, 32);
  if (lk == 0) out[b0 + lr] = s + out_b[0];
}

extern "C" void kernel_launch(void* const* d_in, const int* in_sizes, int n_in,
                              void* d_out, int out_size, void* d_ws, size_t ws_size,
                              hipStream_t stream) {
  const float* X      = (const float*)d_in[0];
  const float* P      = (const float*)d_in[1];
  const float* conv_w = (const float*)d_in[2];
  const float* conv_b = (const float*)d_in[3];
  const float* red_w  = (const float*)d_in[4];
  const float* red_b  = (const float*)d_in[5];
  const float* res_w1 = (const float*)d_in[6];
  const float* res_b1 = (const float*)d_in[7];
  const float* res_w2 = (const float*)d_in[8];
  const float* res_b2 = (const float*)d_in[9];
  const float* out_w  = (const float*)d_in[10];
  const float* out_b  = (const float*)d_in[11];
  float* out = (float*)d_out;

  char* ws = (char*)d_ws;
  __bf16* W_bt  = (__bf16*)(ws);             // 524288 B
  __bf16* W_red = (__bf16*)(ws + 524288);    // 24576 B
  __bf16* W1p   = (__bf16*)(ws + 548864);    // 98304 B
  __bf16* W2p   = (__bf16*)(ws + 647168);    // 98304 B
  float*  Gpad  = (float*)(ws + 745472);     // 192 B
  float*  G     = (float*)(ws + 1048576);    // 23.6 MB

  prep_kernel<<<290, 256, 0, stream>>>(conv_w, conv_b, P, red_w, red_b, res_w1, res_w2,
                                       W_bt, W_red, W1p, W2p, Gpad);
  main_kernel<<<MAIN_BLOCKS, 512, 0, stream>>>(X, W_bt, conv_b, W_red, red_b, G);
  head_kernel<<<BQ/16, 64, 0, stream>>>(G, Gpad, W1p, W2p, res_b1, res_b2, out_w, out_b, out);
}

// Round 14
// 321.765 us; speedup vs baseline: 2.3891x; 2.3891x over previous
//
#include <hip/hip_runtime.h>
#include <hip/hip_bf16.h>

#define SEQ 120
#define CELLS 30          // real cells (ci<5); row ci=5 is pad-only, precomputed
#define RDIM 48
#define BQ 4096
#define MTOT (BQ*CELLS)           // 122880
#define MAIN_BLOCKS (MTOT/64)     // 1920
#define SMB 65536                 // B region base (A dbuf = 2x32KB below)

typedef __bf16 bf16x8 __attribute__((ext_vector_type(8)));
typedef __bf16 bf16x4 __attribute__((ext_vector_type(4)));
typedef float  f32x4  __attribute__((ext_vector_type(4)));

__device__ __forceinline__ float gelu_f(float x){
  return 0.5f * x * (1.0f + erff(x * 0.7071067811865476f));
}
__device__ __forceinline__ bf16x8 pack8(f32x4 a, f32x4 b){
  bf16x8 r;
  r[0]=(__bf16)a[0]; r[1]=(__bf16)a[1]; r[2]=(__bf16)a[2]; r[3]=(__bf16)a[3];
  r[4]=(__bf16)b[0]; r[5]=(__bf16)b[1]; r[6]=(__bf16)b[2]; r[7]=(__bf16)b[3];
  return r;
}
__device__ __forceinline__ bf16x4 pack4(f32x4 a){
  bf16x4 r;
  r[0]=(__bf16)a[0]; r[1]=(__bf16)a[1]; r[2]=(__bf16)a[2]; r[3]=(__bf16)a[3];
  return r;
}

// ---------------- prep: weight repack (fp32->bf16) + pad-cell readout Gpad ----------------
__global__ void prep_kernel(const float* __restrict__ conv_w, const float* __restrict__ conv_b,
                            const float* __restrict__ P,
                            const float* __restrict__ red_w, const float* __restrict__ red_b,
                            const float* __restrict__ res_w1, const float* __restrict__ res_w2,
                            __bf16* __restrict__ W_bt, __bf16* __restrict__ W_red,
                            __bf16* __restrict__ W1p, __bf16* __restrict__ W2p,
                            float* __restrict__ Gpad)
{
  const int b = blockIdx.x, t = threadIdx.x;
  if (b < 256){
    #pragma unroll
    for (int u=0;u<4;u++){
      int k = u*256 + t;
      W_bt[b*1024 + k] = (__bf16)conv_w[b*1024 + (k&255)*4 + (k>>8)];
    }
  } else if (b == 256){
    for (int i=t; i<48*256; i+=256) W_red[i] = (__bf16)red_w[i];
  } else if (b < 273){
    int l = b - 257;
    #pragma unroll
    for (int u=0;u<12;u++){
      int idx = u*256 + t;
      int j = idx >> 6, k = idx & 63;
      W1p[l*3072 + idx] = (k < 48) ? (__bf16)res_w1[(l*48+j)*48 + k] : (__bf16)0.0f;
    }
  } else if (b < 289){
    int l = b - 273;
    #pragma unroll
    for (int u=0;u<12;u++){
      int idx = u*256 + t;
      int j = idx >> 6, k = idx & 63;
      W2p[l*3072 + idx] = (k < 48) ? (__bf16)res_w2[(l*48+j)*48 + k] : (__bf16)0.0f;
    }
  } else {
    __shared__ float tg[256];
    float z = conv_b[t];
    for (int c=0;c<256;c++){
      const float* w = conv_w + t*1024 + c*4;
      z += (w[0]+w[1]+w[2]+w[3]) * P[c];
    }
    tg[t] = gelu_f(z);
    __syncthreads();
    if (t < 48){
      float g = red_b[t];
      for (int o=0;o<256;o++) g += red_w[t*256+o]*tg[o];
      Gpad[t] = gelu_f(g);
    }
  }
}

// ---------------- main: contiguous-A + decoupled-B pipelined GEMM (M=122880,N=256,K=1024)
//   4 positions x 4 sub-steps (BK=64). A: reg-staged per POSITION (8x 1KB fully-contiguous
//   wave reads, issued at s0, consumed by CVTW at s3 -> 3 sub-steps of HBM cover).
//   B: gll into 3-slot LDS rotation, BGLL(S+2) issued at S-end (~2 sub-steps cover),
//   counted vmcnt per sub-step (static FIFO ledger). Compute = pure LDS+MFMA.
//   LDS 160KB exactly. + gelu + fused 256->48 GEMM + gelu -> G ----------------
__global__ __launch_bounds__(512, 1) void main_kernel(
    const float* __restrict__ X, const __bf16* __restrict__ W_bt,
    const float* __restrict__ conv_b, const __bf16* __restrict__ W_red,
    const float* __restrict__ red_b, float* __restrict__ G)
{
  // [0,64K): A bf16 dbuf [2][64 rows][512B]; [64K,160K): B bf16 3 slots [3][256 cols][128B]
  __shared__ __align__(16) char sm[163840];
  const int tid  = threadIdx.x;
  const int lane = tid & 63;
  const int wave = tid >> 6;                 // 8 waves; wm = wave>>2 (M), wn = wave&3 (N)
  const int wm = wave >> 2, wn = wave & 3;
  const int lr = lane & 15, lk = lane >> 4;
  const int m0 = blockIdx.x * 64;

  // ---- A source rows: wave w stages rows w*8..w*8+7, each row = 1KB contiguous (lane*16)
  const char* rowsrcA[8];
  #pragma unroll
  for (int j=0;j<8;j++){
    int row = wave*8 + j;
    int m = m0 + row;
    int bs = m / 30;
    int cs = m - bs*30;
    int ci = cs/6, cj = cs - ci*6;           // ci<5 => all 4 tokens < 120
    rowsrcA[j] = (const char*)(X + ((size_t)bs*SEQ + 24*ci + 2*cj)*256) + lane*16;
  }
  // ---- B source: op jj covers 8 cols; src k-chunk pre-swizzled (m173)
  const char* bsrcB[4];
  #pragma unroll
  for (int jj=0;jj<4;jj++){
    int col = wave*32 + jj*8 + (lane>>3);
    int chunk = (lane&7) ^ (col&7);
    bsrcB[jj] = (const char*)W_bt + (size_t)col*2048 + chunk*16;
  }

  f32x4 acc[2][4];
  #pragma unroll
  for (int a=0;a<2;a++)
    #pragma unroll
    for (int b=0;b<4;b++) acc[a][b] = (f32x4){0.f,0.f,0.f,0.f};

  f32x4 pend[8];
  auto APL = [&](int p){                     // 8 vmem ops/wave, each 1KB contiguous
    const int off = ((p>>1)*12 + (p&1)) << 10;
    #pragma unroll
    for (int j=0;j<8;j++) pend[j] = *(const f32x4*)(rowsrcA[j] + off);
  };
  auto CVTW = [&](int aslot){                // pend -> A slot (bf16, 16B-granule XOR swizzle)
    #pragma unroll
    for (int j=0;j<8;j++){
      int row = wave*8 + j;
      *(bf16x4*)(sm + aslot*32768 + row*512 + ((lane*8) ^ ((row&7)<<4))) = pack4(pend[j]);
    }
  };
  auto BGLL = [&](int S, int slot){          // 4 vmem ops/wave, 1KB linear dest each
    char* dst = sm + SMB + slot*32768 + wave*4096 + lane*16;
    #pragma unroll
    for (int jj=0;jj<4;jj++){
      __builtin_amdgcn_global_load_lds(
        (const __attribute__((address_space(1))) void*)(bsrcB[jj] + S*128),
        (__attribute__((address_space(3))) void*)(dst + jj*1024),
        16, 0, 0);
    }
  };
  auto COMPUTE = [&](int S){
    const int aslot = (S>>2)&1, bslot = S%3, s = S&3;
    #pragma unroll
    for (int ks=0; ks<2; ++ks){
      bf16x8 bv[4];
      #pragma unroll
      for (int ni=0; ni<4; ++ni){
        int col = wn*64 + ni*16 + lr;
        bv[ni] = *(const bf16x8*)(sm + SMB + bslot*32768 + col*128
                                  + (((ks*4+lk)*16) ^ ((col&7)<<4)));
      }
      bf16x8 av[2];
      #pragma unroll
      for (int mi=0; mi<2; ++mi){
        int row = wm*32 + mi*16 + lr;
        av[mi] = *(const bf16x8*)(sm + aslot*32768 + row*512
                                  + ((s*128 + ks*64 + lk*16) ^ ((row&7)<<4)));
      }
      #pragma unroll
      for (int mi=0; mi<2; ++mi)
        #pragma unroll
        for (int ni=0; ni<4; ++ni)
          acc[mi][ni] = __builtin_amdgcn_mfma_f32_16x16x32_bf16(av[mi], bv[ni], acc[mi][ni], 0,0,0);
    }
  };

  #define BARL() do{ asm volatile("s_waitcnt lgkmcnt(0)" ::: "memory"); \
                     __builtin_amdgcn_sched_barrier(0); \
                     __builtin_amdgcn_s_barrier(); \
                     __builtin_amdgcn_sched_barrier(0); }while(0)

  // ---- prologue: A(0)+B0+B1 issued; A0->slot0; B0 drained
  APL(0);
  BGLL(0, 0);
  BGLL(1, 1);
  asm volatile("s_waitcnt vmcnt(8)" ::: "memory");   // APL(0) done (leave B0,B1)
  __builtin_amdgcn_sched_barrier(0);
  CVTW(0);
  asm volatile("s_waitcnt vmcnt(4)" ::: "memory");   // B0 done (leave B1)
  __builtin_amdgcn_sched_barrier(0);
  BARL();

  // ---- 16 sub-steps, statically derived waits
  #pragma unroll
  for (int S=0; S<16; ++S){
    const int p = S>>2, s = S&3;
    COMPUTE(S);
    if (S == 15) break;                      // epilogue follows; nothing left to stage
    BARL();                                  // readers done -> slots reusable
    if (S <= 13) BGLL(S+2, (S+2)%3);
    if (s == 0 && p < 3) APL(p+1);
    if (s == 3 && p < 3) CVTW((p+1)&1);      // pend landed (s2's vmcnt(4) drained APL)
    {
      const int n = (S>=12) ? ((S==14)?0:4) : ((s<=1)?12:4);
      if (n==12)      asm volatile("s_waitcnt vmcnt(12)" ::: "memory");
      else if (n==4)  asm volatile("s_waitcnt vmcnt(4)"  ::: "memory");
      else            asm volatile("s_waitcnt vmcnt(0)"  ::: "memory");
      __builtin_amdgcn_sched_barrier(0);
    }
    BARL();                                  // staged slabs visible to all waves
  }

  // ---- epilogue 1: conv bias + gelu -> Y bf16 [64][512B] at A-slot0 (A3 lives in slot1)
  #pragma unroll
  for (int ni=0; ni<4; ++ni){
    const int col = wn*64 + ni*16 + lr;
    const float cb = conv_b[col];
    #pragma unroll
    for (int mi=0; mi<2; ++mi){
      #pragma unroll
      for (int reg=0; reg<4; ++reg){
        int row = wm*32 + mi*16 + lk*4 + reg;
        float y = gelu_f(acc[mi][ni][reg] + cb);
        *(__bf16*)(sm + ((row*512 + col*2) ^ ((row&7)<<4))) = (__bf16)y;
      }
    }
  }
  __syncthreads();

  // ---- GEMM2: G = gelu(Y @ red_w^T + red_b); waves 0..3 own rows [w*16, w*16+16)
  if (wave < 4){
    f32x4 acc2[3];
    #pragma unroll
    for (int nf=0;nf<3;nf++) acc2[nf] = (f32x4){0.f,0.f,0.f,0.f};
    const int rowY = wave*16 + lr;
    const int keyY = (rowY&7)<<4;
    #pragma unroll
    for (int kk=0; kk<8; ++kk){
      bf16x8 a2 = *(const bf16x8*)(sm + ((rowY*512 + kk*64 + lk*16) ^ keyY));
      #pragma unroll
      for (int nf=0; nf<3; ++nf){
        bf16x8 b2 = *(const bf16x8*)(W_red + (size_t)(nf*16+lr)*256 + kk*32 + lk*8);
        acc2[nf] = __builtin_amdgcn_mfma_f32_16x16x32_bf16(a2, b2, acc2[nf], 0,0,0);
      }
    }
    #pragma unroll
    for (int nf=0; nf<3; ++nf){
      float rb = red_b[nf*16+lr];
      #pragma unroll
      for (int reg=0; reg<4; ++reg){
        int grow = m0 + wave*16 + lk*4 + reg;
        G[(size_t)grow*RDIM + nf*16 + lr] = gelu_f(acc2[nf][reg] + rb);
      }
    }
  }
}

// ---------------- head: pool + 16 residual blocks (bf16 MFMA, K padded to 64) + linear ----------------
__global__ __launch_bounds__(64) void head_kernel(
    const float* __restrict__ G, const float* __restrict__ Gpad,
    const __bf16* __restrict__ W1p, const __bf16* __restrict__ W2p,
    const float* __restrict__ res_b1, const float* __restrict__ res_b2,
    const float* __restrict__ out_w, const float* __restrict__ out_b,
    float* __restrict__ out)
{
  __shared__ __align__(16) char Hs[16*256];
  __shared__ __align__(16) char Ys[16*256];
  const int t = threadIdx.x;
  const int lr = t & 15, lk = t >> 4;
  const int b0 = blockIdx.x * 16;

  {
    int row = t >> 2, j4 = 12 + (t & 3);
    int off = (row*256 + j4*16) ^ ((row&7)<<5);
    *(f32x4*)(Hs + off) = (f32x4){0,0,0,0};
    *(f32x4*)(Ys + off) = (f32x4){0,0,0,0};
  }

  #pragma unroll
  for (int pp=0; pp<3; ++pp){
    int idx = pp*64 + t;
    int b = idx / 12, j4 = idx - b*12;
    f32x4 s = ((const f32x4*)Gpad)[j4] * 6.0f;
    const float* g = G + ((size_t)(b0+b)*CELLS)*RDIM + j4*4;
    #pragma unroll
    for (int c=0;c<CELLS;c++) s += *(const f32x4*)(g + c*RDIM);
    s *= (1.0f/36.0f);
    *(f32x4*)(Hs + ((b*256 + j4*16) ^ ((b&7)<<5))) = s;
  }
  __syncthreads();

  const int rowA = lr;
  const int keyA = (rowA&7)<<5;
  for (int l=0; l<16; ++l){
    bf16x8 a[2];
    #pragma unroll
    for (int kk=0;kk<2;kk++){
      f32x4 u0 = *(const f32x4*)(Hs + ((rowA*256 + kk*128 + lk*32) ^ keyA));
      f32x4 u1 = *(const f32x4*)(Hs + ((rowA*256 + kk*128 + lk*32 + 16) ^ keyA));
      a[kk] = pack8(u0,u1);
    }
    #pragma unroll
    for (int nf=0; nf<3; ++nf){
      f32x4 acc = (f32x4){0,0,0,0};
      #pragma unroll
      for (int kk=0;kk<2;kk++){
        bf16x8 bw = *(const bf16x8*)(W1p + ((size_t)l*48 + nf*16 + lr)*64 + kk*32 + lk*8);
        acc = __builtin_amdgcn_mfma_f32_16x16x32_bf16(a[kk], bw, acc, 0,0,0);
      }
      float bj = res_b1[l*48 + nf*16 + lr];
      #pragma unroll
      for (int reg=0; reg<4; ++reg){
        int row = lk*4 + reg;
        *(float*)(Ys + ((row*256 + (nf*16+lr)*4) ^ ((row&7)<<5))) = gelu_f(acc[reg] + bj);
      }
    }
    __syncthreads();
    bf16x8 a2[2];
    #pragma unroll
    for (int kk=0;kk<2;kk++){
      f32x4 u0 = *(const f32x4*)(Ys + ((rowA*256 + kk*128 + lk*32) ^ keyA));
      f32x4 u1 = *(const f32x4*)(Ys + ((rowA*256 + kk*128 + lk*32 + 16) ^ keyA));
      a2[kk] = pack8(u0,u1);
    }
    #pragma unroll
    for (int nf=0; nf<3; ++nf){
      f32x4 acc = (f32x4){0,0,0,0};
      #pragma unroll
      for (int kk=0;kk<2;kk++){
        bf16x8 bw = *(const bf16x8*)(W2p + ((size_t)l*48 + nf*16 + lr)*64 + kk*32 + lk*8);
        acc = __builtin_amdgcn_mfma_f32_16x16x32_bf16(a2[kk], bw, acc, 0,0,0);
      }
      float bj = res_b2[l*48 + nf*16 + lr];
      #pragma unroll
      for (int reg=0; reg<4; ++reg){
        int row = lk*4 + reg;
        float* hp = (float*)(Hs + ((row*256 + (nf*16+lr)*4) ^ ((row&7)<<5)));
        *hp += acc[reg] + bj;
      }
    }
    __syncthreads();
  }

  float s = 0.f;
  #pragma unroll
  for (int i=0;i<12;i++){
    int j = lk*12 + i;
    s += *(const float*)(Hs + ((lr*256 + j*4) ^ ((lr&7)<<5))) * out_w[j];
  }
  s += __shfl_xor(s, 16);
  s += __shfl_xor(s, 32);
  if (lk == 0) out[b0 + lr] = s + out_b[0];
}

extern "C" void kernel_launch(void* const* d_in, const int* in_sizes, int n_in,
                              void* d_out, int out_size, void* d_ws, size_t ws_size,
                              hipStream_t stream) {
  const float* X      = (const float*)d_in[0];
  const float* P      = (const float*)d_in[1];
  const float* conv_w = (const float*)d_in[2];
  const float* conv_b = (const float*)d_in[3];
  const float* red_w  = (const float*)d_in[4];
  const float* red_b  = (const float*)d_in[5];
  const float* res_w1 = (const float*)d_in[6];
  const float* res_b1 = (const float*)d_in[7];
  const float* res_w2 = (const float*)d_in[8];
  const float* res_b2 = (const float*)d_in[9];
  const float* out_w  = (const float*)d_in[10];
  const float* out_b  = (const float*)d_in[11];
  float* out = (float*)d_out;

  char* ws = (char*)d_ws;
  __bf16* W_bt  = (__bf16*)(ws);             // 524288 B
  __bf16* W_red = (__bf16*)(ws + 524288);    // 24576 B
  __bf16* W1p   = (__bf16*)(ws + 548864);    // 98304 B
  __bf16* W2p   = (__bf16*)(ws + 647168);    // 98304 B
  float*  Gpad  = (float*)(ws + 745472);     // 192 B
  float*  G     = (float*)(ws + 1048576);    // 23.6 MB

  prep_kernel<<<290, 256, 0, stream>>>(conv_w, conv_b, P, red_w, red_b, res_w1, res_w2,
                                       W_bt, W_red, W1p, W2p, Gpad);
  main_kernel<<<MAIN_BLOCKS, 512, 0, stream>>>(X, W_bt, conv_b, W_red, red_b, G);
  head_kernel<<<BQ/16, 64, 0, stream>>>(G, Gpad, W1p, W2p, res_b1, res_b2, out_w, out_b, out);
}